// Round 14
// baseline (335.429 us; speedup 1.0000x reference)
//
#include <hip/hip_runtime.h>
#include <hip/hip_bf16.h>
#include <math.h>

#define DEV __device__ __forceinline__

constexpr int B=8, C=64, DIM=256, HID=128, S=64, NH=16, HD=4, LPIX=784;
constexpr int NPIX = B*LPIX;          // 6272
constexpr int CH   = (NPIX+255)/256;  // 25

constexpr size_t OFF_X1O = 0;
constexpr size_t OFF_T1  = OFF_X1O + (size_t)B*C*LPIX;
constexpr size_t OFF_T2  = OFF_T1  + (size_t)B*HID*LPIX;
constexpr size_t OFF_XA  = OFF_T2  + (size_t)B*C*LPIX;
constexpr size_t OFF_BC2 = OFF_XA  + (size_t)B*DIM*LPIX;
constexpr size_t OFF_WGT = OFF_BC2 + (size_t)B*192*LPIX;        // B*S*L (pure softmax probs)
constexpr size_t OFF_H   = OFF_WGT + (size_t)B*S*LPIX;          // 4 * B*C*S
constexpr size_t OFF_HO  = OFF_H   + (size_t)4*B*C*S;
constexpr size_t OFF_QKV = OFF_HO  + (size_t)B*C*S;
constexpr size_t OFF_O   = OFF_QKV + (size_t)3*B*NH*LPIX*HD;    // 4 * B*L*C partials
constexpr size_t OFF_LS  = OFF_O   + (size_t)4*B*LPIX*C;        // 4 * B*NH*L
constexpr size_t OFF_MID = OFF_LS  + (size_t)4*B*NH*LPIX;

DEV float bnorm(float x, const float* p, int c, int nc){
  float g=p[c], bb=p[nc+c], m=p[2*nc+c], v=p[3*nc+c];
  return (x-m)*(g*rsqrtf(v+1e-5f))+bb;
}
DEV int refl(int p){ int k=p-1; if(k<0)k=-k; if(k>27)k=54-k; return k; }

DEV bool upix(int blk, int tid, int ngroups, int& grp, int& b, int& l){
  grp = blk % ngroups;
  int gidx = (blk/ngroups)*256 + tid;
  if(gidx >= NPIX) return false;
  b = gidx / LPIX; l = gidx % LPIX;
  return true;
}

// ================= bodies =================
DEV void body_dw1t(int bc, int tid, float* xs, const float* X, const float* w, const float* bias, const float* bnp, float* out){
  int c = bc & 63, b = bc >> 6;
  const float* xp = X + ((size_t)(b*DIM+c))*LPIX;
  for(int i=tid;i<LPIX;i+=256) xs[i]=xp[i];
  __syncthreads();
  const float* wc = w + (size_t)c*49;
  float bs = bias[c];
  for(int i=tid;i<LPIX;i+=256){
    int y=i/28, x=i%28;
    float s = bs;
    for(int ky=0;ky<7;ky++){ int iy=y+ky-3; if(iy<0||iy>=28) continue;
      for(int kx=0;kx<7;kx++){ int ix=x+kx-3; if(ix<0||ix>=28) continue;
        s += xs[iy*28+ix]*wc[ky*7+kx]; } }
    out[((size_t)(b*C+c))*LPIX + i] = bnorm(s,bnp,c,C);
  }
}

DEV void body_branch2(int bc, int tid, float* smem, const float* X,
                      const float* h1w,const float* v1w,const float* h2w,const float* v2w,
                      const float* bnp, float* xa){
  int c = bc & 63, b = bc >> 6;
  float* xs  = smem;
  float* mp  = smem+LPIX;
  float* xt  = smem+2*LPIX;
  float* attv= smem+2*LPIX+100;
  const float* xp = X + ((size_t)(b*DIM+64+c))*LPIX;
  for(int i=tid;i<LPIX;i+=256) xs[i]=xp[i];
  __syncthreads();
  for(int i=tid;i<LPIX;i+=256){
    int y=i/28, x=i%28;
    float m=-1e30f;
    for(int dy=-1;dy<=1;dy++){ int iy=y+dy; if(iy<0||iy>=28) continue;
      for(int dx=-1;dx<=1;dx++){ int ix=x+dx; if(ix<0||ix>=28) continue;
        m=fmaxf(m,xs[iy*28+ix]); } }
    mp[i]=m;
  }
  __syncthreads();
  if(tid<100){
    int ii=tid/10, j=tid%10;
    const float fw[4]={0.125f,0.375f,0.375f,0.125f};
    float s=0;
    for(int ky=0;ky<4;ky++){ int rr=refl(3*ii+ky);
      for(int kx=0;kx<4;kx++){ int cc=refl(3*j+kx);
        s += fw[ky]*fw[kx]*mp[rr*28+cc]; } }
    xt[tid]=s;
  }
  __syncthreads();
  if(tid<100){
    int r=tid/10, j=tid%10;
    float s=0;
    for(int kh=0;kh<11;kh++){ int a=r+kh-5; if(a<0||a>=10) continue;
      for(int kw=0;kw<3;kw++){ int b2=j+kw-1; if(b2<0||b2>=10) continue;
        s+=xt[a*10+b2]*h1w[(size_t)c*33+kh*3+kw]; } }
    for(int kh=0;kh<3;kh++){ int a=r+kh-1; if(a<0||a>=10) continue;
      for(int kw=0;kw<11;kw++){ int b2=j+kw-5; if(b2<0||b2>=10) continue;
        s+=xt[a*10+b2]*v1w[(size_t)c*33+kh*11+kw]; } }
    { int t=20*r+j; int r2=t/19, j2=t%19;
      for(int kh=0;kh<11;kh++){ int a=r2+kh-5; if(a<0||a>=10) continue;
        for(int kw=0;kw<3;kw++){ int b2=j2+kw-1; if(b2<0||b2>=19) continue;
          int i2=19*a+b2; int row=i2/20, col=i2%20;
          if(col<10) s+=xt[row*10+col]*h2w[(size_t)c*33+kh*3+kw]; } } }
    { int t=20*j+r; int p=t%19, q=t/19;
      for(int kh=0;kh<3;kh++){ int a=p+kh-1; if(a<0||a>=19) continue;
        for(int kw=0;kw<11;kw++){ int b2=q+kw-5; if(b2<0||b2>=10) continue;
          int i2=19*b2+a; int row=i2/20, col=i2%20;
          if(col<10) s+=xt[col*10+row]*v2w[(size_t)c*33+kh*11+kw]; } } }
    s = bnorm(s,bnp,c,C);
    attv[tid] = 1.f/(1.f+__expf(-s));
  }
  __syncthreads();
  float* dst = xa + ((size_t)(b*DIM+64+c))*LPIX;
  for(int i=tid;i<LPIX;i+=256){
    int y=i/28, x=i%28;
    float a = attv[((y*10)/28)*10 + (x*10)/28];
    dst[i] = xs[i]*a;
  }
}

DEV void body_qkv(int blk, int tid, const float* X, const float* w, float* qkvb){
  int og, b, l; if(!upix(blk, tid, 48, og, b, l)) return;
  int o0 = og*4;
  const float* xp = X + ((size_t)(b*DIM+192))*LPIX + l;
  float s[4]={0,0,0,0};
  for(int c=0;c<C;c++){ float xv=xp[(size_t)c*LPIX];
    for(int t=0;t<4;t++) s[t]+=w[(size_t)(o0+t)*C+c]*xv; }
  int which=o0>>6, rem=o0&63, head=rem>>2;
  float4* dst = (float4*)(qkvb + (size_t)which*B*NH*LPIX*HD + ((size_t)((b*NH+head)*LPIX+l))*HD);
  *dst = make_float4(s[0],s[1],s[2],s[3]);
}

DEV void body_bcdtssd(int blk, int tid, float* smem, const float* X, const float* w, const float* dww,
                      float* bc2, float* wgt){
  int b = blk/48, og = blk%48; int o0=og*4;
  float* bc1s = smem;            // 4*784
  float* dts  = smem + 4*LPIX;   // 4*784
  const float* xp = X + ((size_t)(b*DIM+128))*LPIX;
  const float* w0 = w + (size_t)(o0+0)*C;
  const float* w1 = w + (size_t)(o0+1)*C;
  const float* w2 = w + (size_t)(o0+2)*C;
  const float* w3 = w + (size_t)(o0+3)*C;
  for(int l=tid;l<LPIX;l+=256){
    float s0=0,s1=0,s2=0,s3=0;
    for(int c=0;c<C;c++){
      float xv = xp[(size_t)c*LPIX + l];
      s0+=w0[c]*xv; s1+=w1[c]*xv; s2+=w2[c]*xv; s3+=w3[c]*xv;
    }
    bc1s[0*LPIX+l]=s0; bc1s[1*LPIX+l]=s1; bc1s[2*LPIX+l]=s2; bc1s[3*LPIX+l]=s3;
  }
  __syncthreads();
  for(int i=tid;i<4*LPIX;i+=256){
    int oo=i/LPIX, l=i%LPIX; int y=l/28, x=l%28;
    const float* p = bc1s + oo*LPIX;
    const float* wk = dww + (size_t)(o0+oo)*9;
    float s=0;
    for(int ky=0;ky<3;ky++){ int iy=y+ky-1; if(iy<0||iy>=28) continue;
      for(int kx=0;kx<3;kx++){ int ix=x+kx-1; if(ix<0||ix>=28) continue;
        s += p[iy*28+ix]*wk[ky*3+kx]; } }
    dts[i] = s;
    bc2[((size_t)(b*192+o0+oo))*LPIX + l] = s;
  }
  if(og >= 32){
    __syncthreads();
    int wv = tid>>6, lane = tid&63;
    float* row = dts + wv*LPIX;
    float mx = -1e30f;
    for(int l=lane;l<LPIX;l+=64) mx = fmaxf(mx, row[l]);
    for(int off=32;off;off>>=1) mx = fmaxf(mx, __shfl_xor(mx,off));
    float sum=0;
    for(int l=lane;l<LPIX;l+=64){ float e=__expf(row[l]-mx); row[l]=e; sum+=e; }
    for(int off=32;off;off>>=1) sum += __shfl_xor(sum,off);
    float inv = 1.f/sum;
    int s_ = o0-128+wv;
    float* wp = wgt + ((size_t)(b*S+s_))*LPIX;
    for(int l=lane;l<LPIX;l+=64) wp[l] = row[l]*inv;
  }
}

DEV void body_attn(int blk, int tid, float4* ks, float4* vs, const float* qkvb,
                   float* ob, float* lsb){
  int bh = blk >> 2, ms = blk & 3;
  int b = bh>>4, h = bh&15;
  const float4* q4 = (const float4*)(qkvb + (size_t)bh*LPIX*HD);
  const float4* k4 = (const float4*)(qkvb + (size_t)(B*NH + bh)*LPIX*HD) + ms*196;
  const float4* v4 = (const float4*)(qkvb + (size_t)(2*B*NH + bh)*LPIX*HD) + ms*196;
  for(int i=tid;i<196;i+=256){ ks[i]=k4[i]; vs[i]=v4[i]; }
  __syncthreads();
  if(tid>=196) return;
  const float SC = 0.5f*1.44269504f;
  float4 q[4];
  #pragma unroll
  for(int j=0;j<4;j++){
    q[j]=q4[tid+196*j];
    q[j].x*=SC; q[j].y*=SC; q[j].z*=SC; q[j].w*=SC;
  }
  float ls[4]={0,0,0,0};
  float4 a[4];
  #pragma unroll
  for(int j=0;j<4;j++) a[j]=make_float4(0,0,0,0);
  #pragma unroll 2
  for(int m=0;m<196;m++){
    float4 kv=ks[m], vv=vs[m];
    #pragma unroll
    for(int j=0;j<4;j++){
      float sc = q[j].x*kv.x+q[j].y*kv.y+q[j].z*kv.z+q[j].w*kv.w;
      float p = exp2f(sc);
      ls[j]+=p; a[j].x+=p*vv.x; a[j].y+=p*vv.y; a[j].z+=p*vv.z; a[j].w+=p*vv.w;
    }
  }
  float* obp = ob + (size_t)ms*B*LPIX*C;
  float* lsq = lsb + (size_t)ms*B*NH*LPIX + (size_t)bh*LPIX;
  #pragma unroll
  for(int j=0;j<4;j++){
    int r = tid+196*j;
    *(float4*)(obp + ((size_t)(b*LPIX+r))*C + h*4) = a[j];
    lsq[r] = ls[j];
  }
}

DEV void body_star(int blk, int tid, const float* x1o, const float* f1w,const float* f1b,const float* f2w,const float* f2b,float* t1){
  int jg, b, l; if(!upix(blk, tid, 32, jg, b, l)) return;
  int j0=jg*4;
  const float* xp = x1o + (size_t)b*C*LPIX + l;
  float a[4], g[4];
  for(int t=0;t<4;t++){ a[t]=f1b[j0+t]; g[t]=f2b[j0+t]; }
  for(int c=0;c<C;c++){
    float xv = xp[(size_t)c*LPIX];
    for(int t=0;t<4;t++){ a[t]+=f1w[(size_t)(j0+t)*C+c]*xv; g[t]+=f2w[(size_t)(j0+t)*C+c]*xv; }
  }
  for(int t=0;t<4;t++){
    float av = fminf(fmaxf(a[t],0.f),6.f);
    t1[((size_t)(b*HID+j0+t))*LPIX + l] = av*g[t];
  }
}

DEV void body_gproj(int blk, int tid, const float* t1, const float* gw,const float* gb,const float* bnp,float* t2){
  int cg, b, l; if(!upix(blk, tid, 16, cg, b, l)) return;
  int c0=cg*4;
  const float* tp = t1 + (size_t)b*HID*LPIX + l;
  float s[4]; for(int t=0;t<4;t++) s[t]=gb[c0+t];
  for(int j=0;j<HID;j++){
    float xv = tp[(size_t)j*LPIX];
    for(int t=0;t<4;t++) s[t]+=gw[(size_t)(c0+t)*HID+j]*xv;
  }
  for(int t=0;t<4;t++) t2[((size_t)(b*C+c0+t))*LPIX + l]=bnorm(s[t],bnp,c0+t,C);
}

DEV void body_x4(int blk, int tid, const float* X, const float* ob, const float* lsb,
                 const float* projw, const float* bnp, float* xa){
  int cg, b, l; if(!upix(blk, tid, 16, cg, b, l)) return;
  int c0=cg*4;
  const float* p0 = ob + ((size_t)(b*LPIX+l))*C;
  const float* p1 = p0 + (size_t)B*LPIX*C;
  const float* p2 = p1 + (size_t)B*LPIX*C;
  const float* p3 = p2 + (size_t)B*LPIX*C;
  float s[4]={0,0,0,0};
  for(int h=0;h<NH;h++){
    size_t li = ((size_t)(b*NH+h))*LPIX + l;
    float lsum = lsb[li] + lsb[(size_t)B*NH*LPIX+li] + lsb[(size_t)2*B*NH*LPIX+li] + lsb[(size_t)3*B*NH*LPIX+li];
    float iv = 1.f/lsum;
    for(int kk=0;kk<4;kk++){
      int k = h*4+kk;
      float ov = (p0[k]+p1[k]+p2[k]+p3[k])*iv;
      for(int t=0;t<4;t++) s[t]+=projw[(size_t)(c0+t)*C+k]*ov;
    }
  }
  for(int t=0;t<4;t++){
    float v = s[t] + X[((size_t)(b*DIM+192+c0+t))*LPIX + l];
    xa[((size_t)(b*DIM+192+c0+t))*LPIX + l] = bnorm(v,bnp,c0+t,C);
  }
}

DEV void body_h(int blk, int tid, float* smem, const float* X, const float* wgt, const float* bc2, float* hq){
  int b = blk >> 6, sub = blk & 63;
  int tile = sub >> 2, qq = sub & 3;
  int ct = (tile>>2)*16, st = (tile&3)*16;
  int l0 = qq*196;
  float (*Xs)[197] = (float(*)[197])smem;
  float (*Ws)[197] = (float(*)[197])(smem + 16*197);
  for(int i=tid;i<16*196;i+=256){
    int r=i/196, col=i%196;
    Xs[r][col] = X[((size_t)(b*DIM+128+ct+r))*LPIX + l0 + col];
    Ws[r][col] = wgt[((size_t)(b*S+st+r))*LPIX + l0 + col]
               * bc2[((size_t)(b*192+st+r))*LPIX + l0 + col];
  }
  __syncthreads();
  int tc = tid>>4, ts = tid&15;
  float acc=0;
  #pragma unroll 4
  for(int l=0;l<196;l++) acc += Xs[tc][l]*Ws[ts][l];
  hq[(size_t)qq*B*C*S + ((size_t)(b*C+ct+tc))*S + st+ts] = acc;
}

DEV void body_dw2t(int bc, int tid, float* xs, const float* t2, const float* w, const float* bias, float* xa){
  int c = bc & 63, b = bc >> 6;
  const float* tp = t2 + ((size_t)(b*C+c))*LPIX;
  for(int i=tid;i<LPIX;i+=256) xs[i]=tp[i];
  __syncthreads();
  const float* wc = w + (size_t)c*49;
  float bs = bias[c];
  for(int i=tid;i<LPIX;i+=256){
    int y=i/28, x=i%28;
    float s = bs;
    for(int ky=0;ky<7;ky++){ int iy=y+ky-3; if(iy<0||iy>=28) continue;
      for(int kx=0;kx<7;kx++){ int ix=x+kx-3; if(ix<0||ix>=28) continue;
        s += xs[iy*28+ix]*wc[ky*7+kx]; } }
    xa[((size_t)(b*DIM+c))*LPIX + i] = s;
  }
}

DEV void body_mixho(int blk, int tid, float* smem, const float* hq, const float* hzw,
                    const float* Dp, const float* outw, float* ho){
  int b = blk >> 3, st = (blk & 7) * 8;
  float (*hs2)[8] = (float(*)[8])smem;
  float (*g1s)[8] = (float(*)[8])(smem + C*8);
  for(int i=tid;i<C*8;i+=256){
    int k=i>>3, si=i&7;
    size_t off = ((size_t)(b*C+k))*S + st + si;
    hs2[k][si] = hq[off] + hq[(size_t)B*C*S+off] + hq[(size_t)2*B*C*S+off] + hq[(size_t)3*B*C*S+off];
  }
  __syncthreads();
  float D = Dp[0];
  for(int i=tid;i<C*8;i+=256){
    int c=i>>3, si=i&7;
    float hv=0, zv=0;
    for(int k=0;k<C;k++){ float x=hs2[k][si]; hv+=hzw[(size_t)c*C+k]*x; zv+=hzw[(size_t)(C+c)*C+k]*x; }
    float sil = zv/(1.f+__expf(-zv));
    g1s[c][si]=hv*sil+hv*D;
  }
  __syncthreads();
  for(int i=tid;i<C*8;i+=256){
    int c=i>>3, si=i&7;
    float acc=0;
    for(int k=0;k<C;k++) acc+=outw[(size_t)c*C+k]*g1s[k][si];
    ho[((size_t)(b*C+c))*S + st + si]=acc;
  }
}

DEV void body_x3(int blk, int tid, const float* ho, const float* bc2, float* xa){
  int cg, b, l; if(!upix(blk, tid, 16, cg, b, l)) return;
  int c0=cg*4;
  const float* hp = ho + (size_t)(b*C+c0)*S;
  const float* cm = bc2 + ((size_t)(b*192+64))*LPIX + l;
  float s[4]={0,0,0,0};
  for(int s_=0;s_<S;s_++){
    float cv = cm[(size_t)s_*LPIX];
    for(int t=0;t<4;t++) s[t] += hp[(size_t)t*S+s_]*cv;
  }
  for(int t=0;t<4;t++)
    xa[((size_t)(b*DIM+128+c0+t))*LPIX + l] = s[t];
}

// ================= stage kernels =================
// S1: [0,384)=bcdtssd+softmax  [384,896)=branch2  [896,896+48*CH)=qkv  [..,..+512)=dw1t
__global__ void k_s1(const float* X,
                     const float* bcdt_w, const float* ssd_dw, float* bc2, float* wgt,
                     const float* h1w,const float* v1w,const float* h2w,const float* v2w,const float* bn_mra,
                     const float* qkv_w, float* qkvb,
                     const float* dw1_w,const float* dw1_b,const float* bn_dw1,
                     float* xa, float* x1o){
  __shared__ float smem[8*LPIX];
  int blk = blockIdx.x, tid = threadIdx.x;
  if(blk < 384)            body_bcdtssd(blk, tid, smem, X, bcdt_w, ssd_dw, bc2, wgt);
  else if(blk < 896)       body_branch2(blk-384, tid, smem, X, h1w,v1w,h2w,v2w, bn_mra, xa);
  else if(blk < 896+48*CH) body_qkv(blk-896, tid, X, qkv_w, qkvb);
  else                     body_dw1t(blk-(896+48*CH), tid, smem, X, dw1_w, dw1_b, bn_dw1, x1o);
}

// S2: [0,512)=attn  [512,512+32*CH)=star  [..,..+512)=h
__global__ void k_s2(const float* qkvb, float* ob, float* lsb,
                     const float* x1o, const float* f1w,const float* f1b,const float* f2w,const float* f2b, float* t1,
                     const float* X, const float* wgt, const float* bc2, float* hq){
  __shared__ float4 smem4[1576];   // 6304 floats = max(2*16*197, attn 392*4)
  float* smem = (float*)smem4;
  int blk = blockIdx.x, tid = threadIdx.x;
  if(blk < 512)            body_attn(blk, tid, smem4, smem4+196, qkvb, ob, lsb);
  else if(blk < 512+32*CH) body_star(blk-512, tid, x1o, f1w,f1b,f2w,f2b, t1);
  else                     body_h(blk-(512+32*CH), tid, smem, X, wgt, bc2, hq);
}

// S3: [0,16*CH)=gproj  [16*CH,32*CH)=x4  [32*CH,32*CH+64)=mixho
__global__ void k_s3(const float* t1, const float* gw,const float* gb,const float* bn_g, float* t2,
                     const float* X, const float* ob, const float* lsb,
                     const float* projw, const float* bn_n4, float* xa,
                     const float* hq, const float* hzw, const float* Dp, const float* outw, float* ho){
  __shared__ float smem[2*C*8];
  int blk = blockIdx.x, tid = threadIdx.x;
  if(blk < 16*CH)      body_gproj(blk, tid, t1, gw, gb, bn_g, t2);
  else if(blk < 32*CH) body_x4(blk-16*CH, tid, X, ob, lsb, projw, bn_n4, xa);
  else                 body_mixho(blk-32*CH, tid, smem, hq, hzw, Dp, outw, ho);
}

// S4: [0,512)=dw2t  [512,512+16*CH)=x3
__global__ void k_s4(const float* t2, const float* dw2_w, const float* dw2_b, float* xa,
                     const float* ho, const float* bc2){
  __shared__ float smem[LPIX];
  int blk = blockIdx.x, tid = threadIdx.x;
  if(blk < 512) body_dw2t(blk, tid, smem, t2, dw2_w, dw2_b, xa);
  else          body_x3(blk-512, tid, ho, bc2, xa);
}

// mid: 16 groups x 8 outputs (xa traffic halved)
__global__ void k_mid(const float* xa, const float* m1w, const float* bnp, float* mid){
  int jg, b, l; if(!upix(blockIdx.x, threadIdx.x, 16, jg, b, l)) return;
  int j0=jg*8;
  const float* xp = xa + (size_t)b*DIM*LPIX + l;
  float s[8]={0,0,0,0,0,0,0,0};
  for(int c=0;c<DIM;c++){
    float xv=xp[(size_t)c*LPIX];
    for(int t=0;t<8;t++) s[t]+=m1w[(size_t)(j0+t)*DIM+c]*xv;
  }
  for(int t=0;t<8;t++)
    mid[((size_t)(b*HID+j0+t))*LPIX + l] = fmaxf(bnorm(s[t],bnp,j0+t,HID),0.f);
}

// out: 16 groups x 16 outputs (mid traffic halved)
__global__ void k_out(const float* X, const float* mid, const float* m2w, const float* bnp, float* out){
  int cg, b, l; if(!upix(blockIdx.x, threadIdx.x, 16, cg, b, l)) return;
  int c0=cg*16;
  const float* mp_ = mid + (size_t)b*HID*LPIX + l;
  float s[16];
  #pragma unroll
  for(int t=0;t<16;t++) s[t]=0.f;
  for(int j=0;j<HID;j++){
    float mv=mp_[(size_t)j*LPIX];
    #pragma unroll
    for(int t=0;t<16;t++) s[t]+=m2w[(size_t)(c0+t)*HID+j]*mv;
  }
  #pragma unroll
  for(int t=0;t<16;t++){
    size_t oi = ((size_t)(b*DIM+c0+t))*LPIX + l;
    out[oi] = bnorm(s[t],bnp,c0+t,DIM) + X[oi];
  }
}

extern "C" void kernel_launch(void* const* d_in, const int* in_sizes, int n_in,
                              void* d_out, int out_size, void* d_ws, size_t ws_size,
                              hipStream_t stream) {
  const float* X      = (const float*)d_in[0];
  const float* dw1_w  = (const float*)d_in[1];
  const float* dw1_b  = (const float*)d_in[2];
  const float* bn_dw1 = (const float*)d_in[3];
  const float* f1_w   = (const float*)d_in[4];
  const float* f1_b   = (const float*)d_in[5];
  const float* f2_w   = (const float*)d_in[6];
  const float* f2_b   = (const float*)d_in[7];
  const float* g_w    = (const float*)d_in[8];
  const float* g_b    = (const float*)d_in[9];
  const float* bn_g   = (const float*)d_in[10];
  const float* dw2_w  = (const float*)d_in[11];
  const float* dw2_b  = (const float*)d_in[12];
  const float* hatt1w = (const float*)d_in[13];
  const float* vatt1w = (const float*)d_in[14];
  const float* hatt2w = (const float*)d_in[15];
  const float* vatt2w = (const float*)d_in[16];
  const float* bn_mra = (const float*)d_in[17];
  const float* bcdt_w = (const float*)d_in[18];
  const float* ssd_dw = (const float*)d_in[19];
  const float* hz_w   = (const float*)d_in[20];
  const float* out_w  = (const float*)d_in[21];
  const float* D_p    = (const float*)d_in[23];
  const float* qkv_w  = (const float*)d_in[24];
  const float* proj_w = (const float*)d_in[25];
  const float* bn_n4  = (const float*)d_in[26];
  const float* mlp1_w = (const float*)d_in[27];
  const float* bn_mlp = (const float*)d_in[28];
  const float* mlp2_w = (const float*)d_in[29];
  const float* bn_n1  = (const float*)d_in[30];

  float* ws   = (float*)d_ws;
  float* x1o  = ws+OFF_X1O;  float* t1  = ws+OFF_T1;  float* t2  = ws+OFF_T2;
  float* xa   = ws+OFF_XA;   float* bc2 = ws+OFF_BC2; float* wgt = ws+OFF_WGT;
  float* hq   = ws+OFF_H;    float* ho  = ws+OFF_HO;  float* qkvb= ws+OFF_QKV;
  float* ob   = ws+OFF_O;    float* lsb = ws+OFF_LS;  float* mid = ws+OFF_MID;

  dim3 blk(256);

  k_s1 <<<dim3(896+48*CH+512),blk,0,stream>>>(X, bcdt_w, ssd_dw, bc2, wgt,
                                     hatt1w,vatt1w,hatt2w,vatt2w,bn_mra,
                                     qkv_w, qkvb, dw1_w,dw1_b,bn_dw1, xa, x1o);
  k_s2 <<<dim3(512+32*CH+512),blk,0,stream>>>(qkvb, ob, lsb,
                                     x1o, f1_w,f1_b,f2_w,f2_b, t1,
                                     X, wgt, bc2, hq);
  k_s3 <<<dim3(32*CH+64),blk,0,stream>>>(t1, g_w,g_b,bn_g, t2,
                                     X, ob, lsb, proj_w, bn_n4, xa,
                                     hq, hz_w, D_p, out_w, ho);
  k_s4 <<<dim3(512+16*CH),blk,0,stream>>>(t2, dw2_w, dw2_b, xa, ho, bc2);
  k_mid<<<dim3(16*CH),blk,0,stream>>>(xa,mlp1_w,bn_mlp,mid);
  k_out<<<dim3(16*CH),blk,0,stream>>>(X,mid,mlp2_w,bn_n1,(float*)d_out);
}

// Round 15
// 316.187 us; speedup vs baseline: 1.0609x; 1.0609x over previous
//
#include <hip/hip_runtime.h>
#include <hip/hip_bf16.h>
#include <math.h>

#define DEV __device__ __forceinline__

constexpr int B=8, C=64, DIM=256, HID=128, S=64, NH=16, HD=4, LPIX=784;
constexpr int NPIX = B*LPIX;          // 6272
constexpr int CH   = (NPIX+255)/256;  // 25

constexpr size_t OFF_X1O = 0;
constexpr size_t OFF_T1  = OFF_X1O + (size_t)B*C*LPIX;
constexpr size_t OFF_T2  = OFF_T1  + (size_t)B*HID*LPIX;
constexpr size_t OFF_XA  = OFF_T2  + (size_t)B*C*LPIX;
constexpr size_t OFF_BC2 = OFF_XA  + (size_t)B*DIM*LPIX;
constexpr size_t OFF_WGT = OFF_BC2 + (size_t)B*192*LPIX;        // B*S*L (pure softmax probs)
constexpr size_t OFF_H   = OFF_WGT + (size_t)B*S*LPIX;          // 4 * B*C*S
constexpr size_t OFF_HO  = OFF_H   + (size_t)4*B*C*S;
constexpr size_t OFF_QKV = OFF_HO  + (size_t)B*C*S;
constexpr size_t OFF_O   = OFF_QKV + (size_t)3*B*NH*LPIX*HD;    // 4 * B*L*C partials
constexpr size_t OFF_LS  = OFF_O   + (size_t)4*B*LPIX*C;        // 4 * B*NH*L
constexpr size_t OFF_MID = OFF_LS  + (size_t)4*B*NH*LPIX;

DEV float bnorm(float x, const float* p, int c, int nc){
  float g=p[c], bb=p[nc+c], m=p[2*nc+c], v=p[3*nc+c];
  return (x-m)*(g*rsqrtf(v+1e-5f))+bb;
}
DEV int refl(int p){ int k=p-1; if(k<0)k=-k; if(k>27)k=54-k; return k; }

DEV bool upix(int blk, int tid, int ngroups, int& grp, int& b, int& l){
  grp = blk % ngroups;
  int gidx = (blk/ngroups)*256 + tid;
  if(gidx >= NPIX) return false;
  b = gidx / LPIX; l = gidx % LPIX;
  return true;
}

// ================= bodies =================
DEV void body_dw1t(int bc, int tid, float* xs, const float* X, const float* w, const float* bias, const float* bnp, float* out){
  int c = bc & 63, b = bc >> 6;
  const float* xp = X + ((size_t)(b*DIM+c))*LPIX;
  for(int i=tid;i<LPIX;i+=256) xs[i]=xp[i];
  __syncthreads();
  const float* wc = w + (size_t)c*49;
  float bs = bias[c];
  for(int i=tid;i<LPIX;i+=256){
    int y=i/28, x=i%28;
    float s = bs;
    for(int ky=0;ky<7;ky++){ int iy=y+ky-3; if(iy<0||iy>=28) continue;
      for(int kx=0;kx<7;kx++){ int ix=x+kx-3; if(ix<0||ix>=28) continue;
        s += xs[iy*28+ix]*wc[ky*7+kx]; } }
    out[((size_t)(b*C+c))*LPIX + i] = bnorm(s,bnp,c,C);
  }
}

DEV void body_branch2(int bc, int tid, float* smem, const float* X,
                      const float* h1w,const float* v1w,const float* h2w,const float* v2w,
                      const float* bnp, float* xa){
  int c = bc & 63, b = bc >> 6;
  float* xs  = smem;
  float* mp  = smem+LPIX;
  float* xt  = smem+2*LPIX;
  float* attv= smem+2*LPIX+100;
  const float* xp = X + ((size_t)(b*DIM+64+c))*LPIX;
  for(int i=tid;i<LPIX;i+=256) xs[i]=xp[i];
  __syncthreads();
  for(int i=tid;i<LPIX;i+=256){
    int y=i/28, x=i%28;
    float m=-1e30f;
    for(int dy=-1;dy<=1;dy++){ int iy=y+dy; if(iy<0||iy>=28) continue;
      for(int dx=-1;dx<=1;dx++){ int ix=x+dx; if(ix<0||ix>=28) continue;
        m=fmaxf(m,xs[iy*28+ix]); } }
    mp[i]=m;
  }
  __syncthreads();
  if(tid<100){
    int ii=tid/10, j=tid%10;
    const float fw[4]={0.125f,0.375f,0.375f,0.125f};
    float s=0;
    for(int ky=0;ky<4;ky++){ int rr=refl(3*ii+ky);
      for(int kx=0;kx<4;kx++){ int cc=refl(3*j+kx);
        s += fw[ky]*fw[kx]*mp[rr*28+cc]; } }
    xt[tid]=s;
  }
  __syncthreads();
  if(tid<100){
    int r=tid/10, j=tid%10;
    float s=0;
    for(int kh=0;kh<11;kh++){ int a=r+kh-5; if(a<0||a>=10) continue;
      for(int kw=0;kw<3;kw++){ int b2=j+kw-1; if(b2<0||b2>=10) continue;
        s+=xt[a*10+b2]*h1w[(size_t)c*33+kh*3+kw]; } }
    for(int kh=0;kh<3;kh++){ int a=r+kh-1; if(a<0||a>=10) continue;
      for(int kw=0;kw<11;kw++){ int b2=j+kw-5; if(b2<0||b2>=10) continue;
        s+=xt[a*10+b2]*v1w[(size_t)c*33+kh*11+kw]; } }
    { int t=20*r+j; int r2=t/19, j2=t%19;
      for(int kh=0;kh<11;kh++){ int a=r2+kh-5; if(a<0||a>=10) continue;
        for(int kw=0;kw<3;kw++){ int b2=j2+kw-1; if(b2<0||b2>=19) continue;
          int i2=19*a+b2; int row=i2/20, col=i2%20;
          if(col<10) s+=xt[row*10+col]*h2w[(size_t)c*33+kh*3+kw]; } } }
    { int t=20*j+r; int p=t%19, q=t/19;
      for(int kh=0;kh<3;kh++){ int a=p+kh-1; if(a<0||a>=19) continue;
        for(int kw=0;kw<11;kw++){ int b2=q+kw-5; if(b2<0||b2>=10) continue;
          int i2=19*b2+a; int row=i2/20, col=i2%20;
          if(col<10) s+=xt[col*10+row]*v2w[(size_t)c*33+kh*11+kw]; } } }
    s = bnorm(s,bnp,c,C);
    attv[tid] = 1.f/(1.f+__expf(-s));
  }
  __syncthreads();
  float* dst = xa + ((size_t)(b*DIM+64+c))*LPIX;
  for(int i=tid;i<LPIX;i+=256){
    int y=i/28, x=i%28;
    float a = attv[((y*10)/28)*10 + (x*10)/28];
    dst[i] = xs[i]*a;
  }
}

DEV void body_qkv(int blk, int tid, const float* X, const float* w, float* qkvb){
  int og, b, l; if(!upix(blk, tid, 48, og, b, l)) return;
  int o0 = og*4;
  const float* xp = X + ((size_t)(b*DIM+192))*LPIX + l;
  float s[4]={0,0,0,0};
  for(int c=0;c<C;c++){ float xv=xp[(size_t)c*LPIX];
    for(int t=0;t<4;t++) s[t]+=w[(size_t)(o0+t)*C+c]*xv; }
  int which=o0>>6, rem=o0&63, head=rem>>2;
  float4* dst = (float4*)(qkvb + (size_t)which*B*NH*LPIX*HD + ((size_t)((b*NH+head)*LPIX+l))*HD);
  *dst = make_float4(s[0],s[1],s[2],s[3]);
}

DEV void body_bcdtssd(int blk, int tid, float* smem, const float* X, const float* w, const float* dww,
                      float* bc2, float* wgt){
  int b = blk/48, og = blk%48; int o0=og*4;
  float* bc1s = smem;            // 4*784
  float* dts  = smem + 4*LPIX;   // 4*784
  const float* xp = X + ((size_t)(b*DIM+128))*LPIX;
  const float* w0 = w + (size_t)(o0+0)*C;
  const float* w1 = w + (size_t)(o0+1)*C;
  const float* w2 = w + (size_t)(o0+2)*C;
  const float* w3 = w + (size_t)(o0+3)*C;
  for(int l=tid;l<LPIX;l+=256){
    float s0=0,s1=0,s2=0,s3=0;
    for(int c=0;c<C;c++){
      float xv = xp[(size_t)c*LPIX + l];
      s0+=w0[c]*xv; s1+=w1[c]*xv; s2+=w2[c]*xv; s3+=w3[c]*xv;
    }
    bc1s[0*LPIX+l]=s0; bc1s[1*LPIX+l]=s1; bc1s[2*LPIX+l]=s2; bc1s[3*LPIX+l]=s3;
  }
  __syncthreads();
  for(int i=tid;i<4*LPIX;i+=256){
    int oo=i/LPIX, l=i%LPIX; int y=l/28, x=l%28;
    const float* p = bc1s + oo*LPIX;
    const float* wk = dww + (size_t)(o0+oo)*9;
    float s=0;
    for(int ky=0;ky<3;ky++){ int iy=y+ky-1; if(iy<0||iy>=28) continue;
      for(int kx=0;kx<3;kx++){ int ix=x+kx-1; if(ix<0||ix>=28) continue;
        s += p[iy*28+ix]*wk[ky*3+kx]; } }
    dts[i] = s;
    bc2[((size_t)(b*192+o0+oo))*LPIX + l] = s;
  }
  if(og >= 32){
    __syncthreads();
    int wv = tid>>6, lane = tid&63;
    float* row = dts + wv*LPIX;
    float mx = -1e30f;
    for(int l=lane;l<LPIX;l+=64) mx = fmaxf(mx, row[l]);
    for(int off=32;off;off>>=1) mx = fmaxf(mx, __shfl_xor(mx,off));
    float sum=0;
    for(int l=lane;l<LPIX;l+=64){ float e=__expf(row[l]-mx); row[l]=e; sum+=e; }
    for(int off=32;off;off>>=1) sum += __shfl_xor(sum,off);
    float inv = 1.f/sum;
    int s_ = o0-128+wv;
    float* wp = wgt + ((size_t)(b*S+s_))*LPIX;
    for(int l=lane;l<LPIX;l+=64) wp[l] = row[l]*inv;
  }
}

DEV void body_attn(int blk, int tid, float4* ks, float4* vs, const float* qkvb,
                   float* ob, float* lsb){
  int bh = blk >> 2, ms = blk & 3;
  int b = bh>>4, h = bh&15;
  const float4* q4 = (const float4*)(qkvb + (size_t)bh*LPIX*HD);
  const float4* k4 = (const float4*)(qkvb + (size_t)(B*NH + bh)*LPIX*HD) + ms*196;
  const float4* v4 = (const float4*)(qkvb + (size_t)(2*B*NH + bh)*LPIX*HD) + ms*196;
  for(int i=tid;i<196;i+=256){ ks[i]=k4[i]; vs[i]=v4[i]; }
  __syncthreads();
  if(tid>=196) return;
  const float SC = 0.5f*1.44269504f;
  float4 q[4];
  #pragma unroll
  for(int j=0;j<4;j++){
    q[j]=q4[tid+196*j];
    q[j].x*=SC; q[j].y*=SC; q[j].z*=SC; q[j].w*=SC;
  }
  float ls[4]={0,0,0,0};
  float4 a[4];
  #pragma unroll
  for(int j=0;j<4;j++) a[j]=make_float4(0,0,0,0);
  #pragma unroll 2
  for(int m=0;m<196;m++){
    float4 kv=ks[m], vv=vs[m];
    #pragma unroll
    for(int j=0;j<4;j++){
      float sc = q[j].x*kv.x+q[j].y*kv.y+q[j].z*kv.z+q[j].w*kv.w;
      float p = exp2f(sc);
      ls[j]+=p; a[j].x+=p*vv.x; a[j].y+=p*vv.y; a[j].z+=p*vv.z; a[j].w+=p*vv.w;
    }
  }
  float* obp = ob + (size_t)ms*B*LPIX*C;
  float* lsq = lsb + (size_t)ms*B*NH*LPIX + (size_t)bh*LPIX;
  #pragma unroll
  for(int j=0;j<4;j++){
    int r = tid+196*j;
    *(float4*)(obp + ((size_t)(b*LPIX+r))*C + h*4) = a[j];
    lsq[r] = ls[j];
  }
}

DEV void body_star(int blk, int tid, const float* x1o, const float* f1w,const float* f1b,const float* f2w,const float* f2b,float* t1){
  int jg, b, l; if(!upix(blk, tid, 32, jg, b, l)) return;
  int j0=jg*4;
  const float* xp = x1o + (size_t)b*C*LPIX + l;
  float a[4], g[4];
  for(int t=0;t<4;t++){ a[t]=f1b[j0+t]; g[t]=f2b[j0+t]; }
  for(int c=0;c<C;c++){
    float xv = xp[(size_t)c*LPIX];
    for(int t=0;t<4;t++){ a[t]+=f1w[(size_t)(j0+t)*C+c]*xv; g[t]+=f2w[(size_t)(j0+t)*C+c]*xv; }
  }
  for(int t=0;t<4;t++){
    float av = fminf(fmaxf(a[t],0.f),6.f);
    t1[((size_t)(b*HID+j0+t))*LPIX + l] = av*g[t];
  }
}

DEV void body_gproj(int blk, int tid, const float* t1, const float* gw,const float* gb,const float* bnp,float* t2){
  int cg, b, l; if(!upix(blk, tid, 16, cg, b, l)) return;
  int c0=cg*4;
  const float* tp = t1 + (size_t)b*HID*LPIX + l;
  float s[4]; for(int t=0;t<4;t++) s[t]=gb[c0+t];
  for(int j=0;j<HID;j++){
    float xv = tp[(size_t)j*LPIX];
    for(int t=0;t<4;t++) s[t]+=gw[(size_t)(c0+t)*HID+j]*xv;
  }
  for(int t=0;t<4;t++) t2[((size_t)(b*C+c0+t))*LPIX + l]=bnorm(s[t],bnp,c0+t,C);
}

DEV void body_x4(int blk, int tid, const float* X, const float* ob, const float* lsb,
                 const float* projw, const float* bnp, float* xa){
  int cg, b, l; if(!upix(blk, tid, 16, cg, b, l)) return;
  int c0=cg*4;
  const float* p0 = ob + ((size_t)(b*LPIX+l))*C;
  const float* p1 = p0 + (size_t)B*LPIX*C;
  const float* p2 = p1 + (size_t)B*LPIX*C;
  const float* p3 = p2 + (size_t)B*LPIX*C;
  float s[4]={0,0,0,0};
  for(int h=0;h<NH;h++){
    size_t li = ((size_t)(b*NH+h))*LPIX + l;
    float lsum = lsb[li] + lsb[(size_t)B*NH*LPIX+li] + lsb[(size_t)2*B*NH*LPIX+li] + lsb[(size_t)3*B*NH*LPIX+li];
    float iv = 1.f/lsum;
    for(int kk=0;kk<4;kk++){
      int k = h*4+kk;
      float ov = (p0[k]+p1[k]+p2[k]+p3[k])*iv;
      for(int t=0;t<4;t++) s[t]+=projw[(size_t)(c0+t)*C+k]*ov;
    }
  }
  for(int t=0;t<4;t++){
    float v = s[t] + X[((size_t)(b*DIM+192+c0+t))*LPIX + l];
    xa[((size_t)(b*DIM+192+c0+t))*LPIX + l] = bnorm(v,bnp,c0+t,C);
  }
}

DEV void body_h(int blk, int tid, float* smem, const float* X, const float* wgt, const float* bc2, float* hq){
  int b = blk >> 6, sub = blk & 63;
  int tile = sub >> 2, qq = sub & 3;
  int ct = (tile>>2)*16, st = (tile&3)*16;
  int l0 = qq*196;
  float (*Xs)[197] = (float(*)[197])smem;
  float (*Ws)[197] = (float(*)[197])(smem + 16*197);
  for(int i=tid;i<16*196;i+=256){
    int r=i/196, col=i%196;
    Xs[r][col] = X[((size_t)(b*DIM+128+ct+r))*LPIX + l0 + col];
    Ws[r][col] = wgt[((size_t)(b*S+st+r))*LPIX + l0 + col]
               * bc2[((size_t)(b*192+st+r))*LPIX + l0 + col];
  }
  __syncthreads();
  int tc = tid>>4, ts = tid&15;
  float acc=0;
  #pragma unroll 4
  for(int l=0;l<196;l++) acc += Xs[tc][l]*Ws[ts][l];
  hq[(size_t)qq*B*C*S + ((size_t)(b*C+ct+tc))*S + st+ts] = acc;
}

DEV void body_dw2t(int bc, int tid, float* xs, const float* t2, const float* w, const float* bias, float* xa){
  int c = bc & 63, b = bc >> 6;
  const float* tp = t2 + ((size_t)(b*C+c))*LPIX;
  for(int i=tid;i<LPIX;i+=256) xs[i]=tp[i];
  __syncthreads();
  const float* wc = w + (size_t)c*49;
  float bs = bias[c];
  for(int i=tid;i<LPIX;i+=256){
    int y=i/28, x=i%28;
    float s = bs;
    for(int ky=0;ky<7;ky++){ int iy=y+ky-3; if(iy<0||iy>=28) continue;
      for(int kx=0;kx<7;kx++){ int ix=x+kx-3; if(ix<0||ix>=28) continue;
        s += xs[iy*28+ix]*wc[ky*7+kx]; } }
    xa[((size_t)(b*DIM+c))*LPIX + i] = s;
  }
}

DEV void body_mixho(int blk, int tid, float* smem, const float* hq, const float* hzw,
                    const float* Dp, const float* outw, float* ho){
  int b = blk >> 3, st = (blk & 7) * 8;
  float (*hs2)[8] = (float(*)[8])smem;
  float (*g1s)[8] = (float(*)[8])(smem + C*8);
  for(int i=tid;i<C*8;i+=256){
    int k=i>>3, si=i&7;
    size_t off = ((size_t)(b*C+k))*S + st + si;
    hs2[k][si] = hq[off] + hq[(size_t)B*C*S+off] + hq[(size_t)2*B*C*S+off] + hq[(size_t)3*B*C*S+off];
  }
  __syncthreads();
  float D = Dp[0];
  for(int i=tid;i<C*8;i+=256){
    int c=i>>3, si=i&7;
    float hv=0, zv=0;
    for(int k=0;k<C;k++){ float x=hs2[k][si]; hv+=hzw[(size_t)c*C+k]*x; zv+=hzw[(size_t)(C+c)*C+k]*x; }
    float sil = zv/(1.f+__expf(-zv));
    g1s[c][si]=hv*sil+hv*D;
  }
  __syncthreads();
  for(int i=tid;i<C*8;i+=256){
    int c=i>>3, si=i&7;
    float acc=0;
    for(int k=0;k<C;k++) acc+=outw[(size_t)c*C+k]*g1s[k][si];
    ho[((size_t)(b*C+c))*S + st + si]=acc;
  }
}

DEV void body_x3(int blk, int tid, const float* ho, const float* bc2, float* xa){
  int cg, b, l; if(!upix(blk, tid, 16, cg, b, l)) return;
  int c0=cg*4;
  const float* hp = ho + (size_t)(b*C+c0)*S;
  const float* cm = bc2 + ((size_t)(b*192+64))*LPIX + l;
  float s[4]={0,0,0,0};
  for(int s_=0;s_<S;s_++){
    float cv = cm[(size_t)s_*LPIX];
    for(int t=0;t<4;t++) s[t] += hp[(size_t)t*S+s_]*cv;
  }
  for(int t=0;t<4;t++)
    xa[((size_t)(b*DIM+128+c0+t))*LPIX + l] = s[t];
}

// ================= stage kernels =================
// S1: [0,384)=bcdtssd+softmax  [384,896)=branch2  [896,896+48*CH)=qkv  [..,..+512)=dw1t
__global__ void k_s1(const float* X,
                     const float* bcdt_w, const float* ssd_dw, float* bc2, float* wgt,
                     const float* h1w,const float* v1w,const float* h2w,const float* v2w,const float* bn_mra,
                     const float* qkv_w, float* qkvb,
                     const float* dw1_w,const float* dw1_b,const float* bn_dw1,
                     float* xa, float* x1o){
  __shared__ float smem[8*LPIX];
  int blk = blockIdx.x, tid = threadIdx.x;
  if(blk < 384)            body_bcdtssd(blk, tid, smem, X, bcdt_w, ssd_dw, bc2, wgt);
  else if(blk < 896)       body_branch2(blk-384, tid, smem, X, h1w,v1w,h2w,v2w, bn_mra, xa);
  else if(blk < 896+48*CH) body_qkv(blk-896, tid, X, qkv_w, qkvb);
  else                     body_dw1t(blk-(896+48*CH), tid, smem, X, dw1_w, dw1_b, bn_dw1, x1o);
}

// S2: [0,512)=attn  [512,512+32*CH)=star  [..,..+512)=h
__global__ void k_s2(const float* qkvb, float* ob, float* lsb,
                     const float* x1o, const float* f1w,const float* f1b,const float* f2w,const float* f2b, float* t1,
                     const float* X, const float* wgt, const float* bc2, float* hq){
  __shared__ float4 smem4[1576];
  float* smem = (float*)smem4;
  int blk = blockIdx.x, tid = threadIdx.x;
  if(blk < 512)            body_attn(blk, tid, smem4, smem4+196, qkvb, ob, lsb);
  else if(blk < 512+32*CH) body_star(blk-512, tid, x1o, f1w,f1b,f2w,f2b, t1);
  else                     body_h(blk-(512+32*CH), tid, smem, X, wgt, bc2, hq);
}

// S3: [0,16*CH)=gproj  [16*CH,32*CH)=x4  [32*CH,32*CH+64)=mixho
__global__ void k_s3(const float* t1, const float* gw,const float* gb,const float* bn_g, float* t2,
                     const float* X, const float* ob, const float* lsb,
                     const float* projw, const float* bn_n4, float* xa,
                     const float* hq, const float* hzw, const float* Dp, const float* outw, float* ho){
  __shared__ float smem[2*C*8];
  int blk = blockIdx.x, tid = threadIdx.x;
  if(blk < 16*CH)      body_gproj(blk, tid, t1, gw, gb, bn_g, t2);
  else if(blk < 32*CH) body_x4(blk-16*CH, tid, X, ob, lsb, projw, bn_n4, xa);
  else                 body_mixho(blk-32*CH, tid, smem, hq, hzw, Dp, outw, ho);
}

// S4: [0,512)=dw2t  [512,512+16*CH)=x3
__global__ void k_s4(const float* t2, const float* dw2_w, const float* dw2_b, float* xa,
                     const float* ho, const float* bc2){
  __shared__ float smem[LPIX];
  int blk = blockIdx.x, tid = threadIdx.x;
  if(blk < 512) body_dw2t(blk, tid, smem, t2, dw2_w, dw2_b, xa);
  else          body_x3(blk-512, tid, ho, bc2, xa);
}

// mid: 32 groups x 4 outputs (800 blocks — reverted from 16x8)
__global__ void k_mid(const float* xa, const float* m1w, const float* bnp, float* mid){
  int jg, b, l; if(!upix(blockIdx.x, threadIdx.x, 32, jg, b, l)) return;
  int j0=jg*4;
  const float* xp = xa + (size_t)b*DIM*LPIX + l;
  float s[4]={0,0,0,0};
  for(int c=0;c<DIM;c++){
    float xv=xp[(size_t)c*LPIX];
    for(int t=0;t<4;t++) s[t]+=m1w[(size_t)(j0+t)*DIM+c]*xv;
  }
  for(int t=0;t<4;t++)
    mid[((size_t)(b*HID+j0+t))*LPIX + l] = fmaxf(bnorm(s[t],bnp,j0+t,HID),0.f);
}

// out: 32 groups x 8 outputs (800 blocks — reverted from 16x16)
__global__ void k_out(const float* X, const float* mid, const float* m2w, const float* bnp, float* out){
  int cg, b, l; if(!upix(blockIdx.x, threadIdx.x, 32, cg, b, l)) return;
  int c0=cg*8;
  const float* mp_ = mid + (size_t)b*HID*LPIX + l;
  float s[8]={0,0,0,0,0,0,0,0};
  for(int j=0;j<HID;j++){
    float mv=mp_[(size_t)j*LPIX];
    for(int t=0;t<8;t++) s[t]+=m2w[(size_t)(c0+t)*HID+j]*mv;
  }
  for(int t=0;t<8;t++){
    size_t oi = ((size_t)(b*DIM+c0+t))*LPIX + l;
    out[oi] = bnorm(s[t],bnp,c0+t,DIM) + X[oi];
  }
}

extern "C" void kernel_launch(void* const* d_in, const int* in_sizes, int n_in,
                              void* d_out, int out_size, void* d_ws, size_t ws_size,
                              hipStream_t stream) {
  const float* X      = (const float*)d_in[0];
  const float* dw1_w  = (const float*)d_in[1];
  const float* dw1_b  = (const float*)d_in[2];
  const float* bn_dw1 = (const float*)d_in[3];
  const float* f1_w   = (const float*)d_in[4];
  const float* f1_b   = (const float*)d_in[5];
  const float* f2_w   = (const float*)d_in[6];
  const float* f2_b   = (const float*)d_in[7];
  const float* g_w    = (const float*)d_in[8];
  const float* g_b    = (const float*)d_in[9];
  const float* bn_g   = (const float*)d_in[10];
  const float* dw2_w  = (const float*)d_in[11];
  const float* dw2_b  = (const float*)d_in[12];
  const float* hatt1w = (const float*)d_in[13];
  const float* vatt1w = (const float*)d_in[14];
  const float* hatt2w = (const float*)d_in[15];
  const float* vatt2w = (const float*)d_in[16];
  const float* bn_mra = (const float*)d_in[17];
  const float* bcdt_w = (const float*)d_in[18];
  const float* ssd_dw = (const float*)d_in[19];
  const float* hz_w   = (const float*)d_in[20];
  const float* out_w  = (const float*)d_in[21];
  const float* D_p    = (const float*)d_in[23];
  const float* qkv_w  = (const float*)d_in[24];
  const float* proj_w = (const float*)d_in[25];
  const float* bn_n4  = (const float*)d_in[26];
  const float* mlp1_w = (const float*)d_in[27];
  const float* bn_mlp = (const float*)d_in[28];
  const float* mlp2_w = (const float*)d_in[29];
  const float* bn_n1  = (const float*)d_in[30];

  float* ws   = (float*)d_ws;
  float* x1o  = ws+OFF_X1O;  float* t1  = ws+OFF_T1;  float* t2  = ws+OFF_T2;
  float* xa   = ws+OFF_XA;   float* bc2 = ws+OFF_BC2; float* wgt = ws+OFF_WGT;
  float* hq   = ws+OFF_H;    float* ho  = ws+OFF_HO;  float* qkvb= ws+OFF_QKV;
  float* ob   = ws+OFF_O;    float* lsb = ws+OFF_LS;  float* mid = ws+OFF_MID;

  dim3 blk(256);

  k_s1 <<<dim3(896+48*CH+512),blk,0,stream>>>(X, bcdt_w, ssd_dw, bc2, wgt,
                                     hatt1w,vatt1w,hatt2w,vatt2w,bn_mra,
                                     qkv_w, qkvb, dw1_w,dw1_b,bn_dw1, xa, x1o);
  k_s2 <<<dim3(512+32*CH+512),blk,0,stream>>>(qkvb, ob, lsb,
                                     x1o, f1_w,f1_b,f2_w,f2_b, t1,
                                     X, wgt, bc2, hq);
  k_s3 <<<dim3(32*CH+64),blk,0,stream>>>(t1, g_w,g_b,bn_g, t2,
                                     X, ob, lsb, proj_w, bn_n4, xa,
                                     hq, hz_w, D_p, out_w, ho);
  k_s4 <<<dim3(512+16*CH),blk,0,stream>>>(t2, dw2_w, dw2_b, xa, ho, bc2);
  k_mid<<<dim3(32*CH),blk,0,stream>>>(xa,mlp1_w,bn_mlp,mid);
  k_out<<<dim3(32*CH),blk,0,stream>>>(X,mid,mlp2_w,bn_n1,(float*)d_out);
}